// Round 2
// baseline (556.590 us; speedup 1.0000x reference)
//
#include <hip/hip_runtime.h>
#include <hip/hip_bf16.h>

typedef unsigned short u16;
typedef __bf16 bf16x8 __attribute__((ext_vector_type(8)));
typedef float floatx4 __attribute__((ext_vector_type(4)));
typedef unsigned uintx4 __attribute__((ext_vector_type(4)));
typedef unsigned short ushortx4 __attribute__((ext_vector_type(4)));

static constexpr int D = 128;

__device__ inline float bflo(unsigned u) { return __uint_as_float(u << 16); }
__device__ inline float bfhi(unsigned u) { return __uint_as_float(u & 0xffff0000u); }
__device__ inline unsigned packbf(float a, float b) {
    unsigned lo = __hip_bfloat16_raw(__float2bfloat16(a)).x;
    unsigned hi = __hip_bfloat16_raw(__float2bfloat16(b)).x;
    return lo | (hi << 16);
}

// ---------------- zero ints ----------------
__global__ void zero_int_kernel(int* __restrict__ p, int n) {
    int i = blockIdx.x * blockDim.x + threadIdx.x;
    int stride = gridDim.x * blockDim.x;
    for (; i < n; i += stride) p[i] = 0;
}

// ---------------- convert x fp32 -> bf16 ----------------
// x is read exactly once -> nontemporal load. xb is the one hot buffer with
// massive reuse (gathered ~30x/row by aggregate) -> normal store so it lands
// warm in L2/L3 and STAYS there (everything else is marked evict-first).
__global__ void convert_x_kernel(const float* __restrict__ x, u16* __restrict__ xb, int n4) {
    int i = blockIdx.x * blockDim.x + threadIdx.x;
    int stride = gridDim.x * blockDim.x;
    for (; i < n4; i += stride) {
        floatx4 v = __builtin_nontemporal_load((const floatx4*)x + i);
        ushortx4 o;
        o.x = __hip_bfloat16_raw(__float2bfloat16(v.x)).x;
        o.y = __hip_bfloat16_raw(__float2bfloat16(v.y)).x;
        o.z = __hip_bfloat16_raw(__float2bfloat16(v.z)).x;
        o.w = __hip_bfloat16_raw(__float2bfloat16(v.w)).x;
        *((ushortx4*)xb + i) = o;
    }
}

// ---------------- per-dst counts: all three edge types in one launch ----------------
__global__ void count3_kernel(const int* __restrict__ dst0, const int* __restrict__ dst1,
                              const int* __restrict__ dst2, int* __restrict__ counts,
                              int E, int N) {
    int i = blockIdx.x * blockDim.x + threadIdx.x;
    if (i < E) {
        atomicAdd(&counts[__builtin_nontemporal_load(dst0 + i)], 1);
    } else if (i < 2 * E) {
        atomicAdd(&counts[N + __builtin_nontemporal_load(dst1 + (i - E))], 1);
    } else if (i < 3 * E) {
        atomicAdd(&counts[2 * N + __builtin_nontemporal_load(dst2 + (i - 2 * E))], 1);
    }
}

// ---------------- offsets: wave scan + one atomic per wave ----------------
// CSR segments need only be disjoint+contiguous per node, not sorted.
__global__ __launch_bounds__(256) void offs_kernel(const int* __restrict__ counts,
                                                   int* __restrict__ offs,
                                                   int* __restrict__ cursor,
                                                   int* __restrict__ counters,
                                                   int N, int bpt) {
    int type = blockIdx.x / bpt;
    int n = (blockIdx.x - type * bpt) * 256 + threadIdx.x;
    int lane = threadIdx.x & 63;
    int i = type * N + n;
    int v = (n < N) ? counts[i] : 0;
    int incl = v;
#pragma unroll
    for (int d = 1; d < 64; d <<= 1) {
        int t = __shfl_up(incl, d, 64);
        if (lane >= d) incl += t;
    }
    int total = __shfl(incl, 63, 64);
    int base = 0;
    if (lane == 63) base = atomicAdd(&counters[type], total);
    base = __shfl(base, 63, 64);
    int off = base + incl - v;
    if (n < N) {
        offs[i] = off;
        cursor[i] = off;
    }
}

// ---------------- CSR scatter (all three edge types, one launch) ----------------
__global__ void scatter3_kernel(const int* __restrict__ dst0, const int* __restrict__ src0,
                                const int* __restrict__ dst1, const int* __restrict__ src1,
                                const int* __restrict__ dst2, const int* __restrict__ src2,
                                int* __restrict__ cursor,
                                int* __restrict__ csr0, int* __restrict__ csr1,
                                int* __restrict__ csr2, int E, int N) {
    int i = blockIdx.x * blockDim.x + threadIdx.x;
    if (i < E) {
        int d = __builtin_nontemporal_load(dst0 + i);
        int pos = atomicAdd(&cursor[d], 1);
        __builtin_nontemporal_store(__builtin_nontemporal_load(src0 + i), csr0 + pos);
    } else if (i < 2 * E) {
        int e = i - E;
        int d = __builtin_nontemporal_load(dst1 + e);
        int pos = atomicAdd(&cursor[N + d], 1);
        __builtin_nontemporal_store(__builtin_nontemporal_load(src1 + e * 2), csr1 + pos * 2);
        __builtin_nontemporal_store(__builtin_nontemporal_load(src1 + e * 2 + 1), csr1 + pos * 2 + 1);
    } else if (i < 3 * E) {
        int e = i - 2 * E;
        int d = __builtin_nontemporal_load(dst2 + e);
        int pos = atomicAdd(&cursor[2 * N + d], 1);
        __builtin_nontemporal_store(__builtin_nontemporal_load(src2 + e * 3), csr2 + pos * 3);
        __builtin_nontemporal_store(__builtin_nontemporal_load(src2 + e * 3 + 1), csr2 + pos * 3 + 1);
        __builtin_nontemporal_store(__builtin_nontemporal_load(src2 + e * 3 + 2), csr2 + pos * 3 + 2);
    }
}

// ---------------- per-node aggregation: one row per wave, lane owns 2 columns ----------------
// CSR reads and AG writes are single-use streams -> nontemporal (evict-first),
// so the x gather (the only reused data) keeps L2/L3 to itself.
template <int A>
__device__ inline void agg_wave(const u16* __restrict__ xb, const int* __restrict__ csr,
                                int o0, int deg, int lane, u16* __restrict__ outp) {
    constexpr int CH_E = (A == 3) ? 8 : 16;  // edges per chunk
    constexpr int CH = CH_E * A;             // csr items per chunk (<=64 lanes)
    float acc[A][2];
#pragma unroll
    for (int s = 0; s < A; ++s) {
        acc[s][0] = 0.f;
        acc[s][1] = 0.f;
    }
    const int items = deg * A;
    const int base = o0 * A;

    for (int e0 = 0; e0 < deg; e0 += CH_E) {
        int rv = 0;
        int ib = e0 * A;
        if (lane < CH && ib + lane < items) rv = __builtin_nontemporal_load(csr + base + ib + lane);
        int erem = deg - e0;  // wave-uniform
#pragma unroll
        for (int ke = 0; ke < CH_E; ++ke) {
            if (ke < erem) {
#pragma unroll
                for (int s = 0; s < A; ++s) {
                    int r = __builtin_amdgcn_readlane(rv, ke * A + s);  // SGPR row id
                    const unsigned u =
                        ((const unsigned*)(xb + ((size_t)(unsigned)r << 7)))[lane];
                    acc[s][0] += bflo(u);
                    acc[s][1] += bfhi(u);
                }
            }
        }
    }

    float norm = (deg > 0) ? 1.0f / (float)deg : 0.0f;
#pragma unroll
    for (int s = 0; s < A; ++s) {
        unsigned o = packbf(acc[s][0] * norm, acc[s][1] * norm);
        __builtin_nontemporal_store(o, (unsigned*)(outp + s * D) + lane);
    }
}

__global__ __launch_bounds__(256) void aggregate_kernel(
    const u16* __restrict__ xb, const int* __restrict__ counts, const int* __restrict__ offs,
    const int* __restrict__ csr0, const int* __restrict__ csr1, const int* __restrict__ csr2,
    u16* __restrict__ AG, int n0, int M, int N) {
    int w = __builtin_amdgcn_readfirstlane(threadIdx.x >> 6);
    int gw = blockIdx.x * 4 + w;
    int lane = threadIdx.x & 63;
    if (gw >= 3 * M) return;
    int type = (gw >= 2 * M) ? 2 : (gw >= M) ? 1 : 0;
    int l = gw - type * M;
    int n = n0 + l;
    u16* outp = AG + (size_t)l * 768;
    if (type == 0) {
        int o0 = __builtin_amdgcn_readfirstlane(offs[n]);
        int dg = __builtin_amdgcn_readfirstlane(counts[n]);
        agg_wave<1>(xb, csr0, o0, dg, lane, outp);
    } else if (type == 1) {
        int o0 = __builtin_amdgcn_readfirstlane(offs[N + n]);
        int dg = __builtin_amdgcn_readfirstlane(counts[N + n]);
        agg_wave<2>(xb, csr1, o0, dg, lane, outp + 128);
    } else {
        int o0 = __builtin_amdgcn_readfirstlane(offs[2 * N + n]);
        int dg = __builtin_amdgcn_readfirstlane(counts[2 * N + n]);
        agg_wave<3>(xb, csr2, o0, dg, lane, outp + 384);
    }
}

// ---------------- pack fp32 weights into bf16 MFMA B-fragment order (one launch) ----------------
// Wp layout (u16): [0,16384)=WC^T, [16384,32768)=WA0, [32768,65536)=WA1, [65536,163840... )=WA2
__global__ void pack_all_kernel(const float* __restrict__ WC, const float* __restrict__ WA0,
                                const float* __restrict__ WA1, const float* __restrict__ WA2,
                                u16* __restrict__ Wp) {
    int c = blockIdx.x * blockDim.x + threadIdx.x;  // 0 .. 14335 chunks
    if (c >= 14336) return;
    const float* W;
    int K, transposed, cl;
    u16* out;
    if (c < 2048) {
        W = WC; K = 128; transposed = 1; cl = c; out = Wp;
    } else if (c < 4096) {
        W = WA0; K = 128; transposed = 0; cl = c - 2048; out = Wp + 16384;
    } else if (c < 8192) {
        W = WA1; K = 256; transposed = 0; cl = c - 4096; out = Wp + 32768;
    } else {
        W = WA2; K = 384; transposed = 0; cl = c - 8192; out = Wp + 65536;
    }
    int s = cl >> 9, rem = cl & 511, t = rem >> 6, l = rem & 63;
    int kbase = 32 * s + ((l >> 4) * 8);
    int n = 16 * t + (l & 15);
#pragma unroll
    for (int j = 0; j < 8; ++j) {
        int k = kbase + j;
        float w = transposed ? W[n * K + k] : W[k * D + n];
        out[(size_t)cl * 8 + j] = __hip_bfloat16_raw(__float2bfloat16(w)).x;
    }
}

// ---------------- fused final GEMM: out = [x | AG] @ [WC^T; WA*] + bC ----------------
__global__ __launch_bounds__(256) void final_gemm_kernel(
    const u16* __restrict__ xb, const u16* __restrict__ AG, const u16* __restrict__ Wp,
    const float* __restrict__ bC, float* __restrict__ out, int n0, int M) {
    constexpr int KSTEPS = 14;  // 896 / 64
    alignas(16) __shared__ u16 As[128][72];
    alignas(16) __shared__ u16 Bs[8192];

    const int tid = threadIdx.x;
    const int wave = tid >> 6;
    const int lane = tid & 63;
    const int m0 = blockIdx.x * 128;

    floatx4 acc[2][8];
#pragma unroll
    for (int s = 0; s < 2; ++s)
#pragma unroll
        for (int t = 0; t < 8; ++t) acc[s][t] = floatx4{0.f, 0.f, 0.f, 0.f};

    for (int ks = 0; ks < KSTEPS; ++ks) {
#pragma unroll
        for (int it = 0; it < 4; ++it) {
            int chunk = tid + it * 256;
            int row = chunk >> 3, part = chunk & 7;
            int e = m0 + row;
            uintx4 v;
            if (ks < 2) {
                int g = (e < M) ? (n0 + e) : n0;
                v = *(const uintx4*)(xb + (size_t)g * D + ks * 64 + part * 8);
            } else {
                int l = (e < M) ? e : 0;
                // AG is read exactly once -> evict-first
                v = __builtin_nontemporal_load(
                    (const uintx4*)(AG + (size_t)l * 768 + (ks - 2) * 64 + part * 8));
            }
            *(uintx4*)(&As[row][part * 8]) = v;
        }
        {
            const uintx4* sB = (const uintx4*)(Wp + (size_t)ks * 8192);
            uintx4* dB = (uintx4*)Bs;
#pragma unroll
            for (int it = 0; it < 4; ++it) dB[tid + it * 256] = sB[tid + it * 256];
        }
        __syncthreads();
#pragma unroll
        for (int sub = 0; sub < 2; ++sub) {
            bf16x8 bfrag[8];
#pragma unroll
            for (int t = 0; t < 8; ++t)
                bfrag[t] = *(const bf16x8*)(&Bs[((sub * 8 + t) * 64 + lane) * 8]);
#pragma unroll
            for (int strip = 0; strip < 2; ++strip) {
                int row = wave * 32 + strip * 16 + (lane & 15);
                bf16x8 afrag = *(const bf16x8*)(&As[row][sub * 32 + ((lane >> 4) * 8)]);
#pragma unroll
                for (int t = 0; t < 8; ++t)
                    acc[strip][t] = __builtin_amdgcn_mfma_f32_16x16x32_bf16(
                        afrag, bfrag[t], acc[strip][t], 0, 0, 0);
            }
        }
        __syncthreads();
    }

#pragma unroll
    for (int strip = 0; strip < 2; ++strip) {
#pragma unroll
        for (int r = 0; r < 4; ++r) {
            int row = wave * 32 + strip * 16 + (lane >> 4) * 4 + r;
            int e = m0 + row;
            if (e >= M) continue;
            size_t base = (size_t)(n0 + e) * D;
#pragma unroll
            for (int t = 0; t < 8; ++t) {
                int col = 16 * t + (lane & 15);
                // out is written once, never re-read
                __builtin_nontemporal_store(acc[strip][t][r] + bC[col], out + base + col);
            }
        }
    }
}

extern "C" void kernel_launch(void* const* d_in, const int* in_sizes, int n_in,
                              void* d_out, int out_size, void* d_ws, size_t ws_size,
                              hipStream_t stream) {
    const float* x = (const float*)d_in[0];
    const int* src0 = (const int*)d_in[1];
    const int* dst0 = (const int*)d_in[2];
    const int* src1 = (const int*)d_in[3];
    const int* dst1 = (const int*)d_in[4];
    const int* src2 = (const int*)d_in[5];
    const int* dst2 = (const int*)d_in[6];
    const float* WA0 = (const float*)d_in[7];
    const float* WA1 = (const float*)d_in[8];
    const float* WA2 = (const float*)d_in[9];
    const float* WC = (const float*)d_in[10];
    const float* bC = (const float*)d_in[11];

    const int N = in_sizes[0] / D;  // 100000
    const int E = in_sizes[2];      // 500000

    auto align256 = [](size_t v) { return (v + 255) & ~(size_t)255; };
    char* ws = (char*)d_ws;
    size_t ofs = 0;
    u16* xb = (u16*)(ws + ofs);      ofs = align256(ofs + (size_t)N * D * sizeof(u16));
    int* counts = (int*)(ws + ofs);  ofs = align256(ofs + ((size_t)3 * N + 4) * sizeof(int));
    int* counters = counts + 3 * N;  // 3 ints, zeroed with counts
    int* offs = (int*)(ws + ofs);    ofs = align256(ofs + (size_t)3 * N * sizeof(int));
    int* cursor = (int*)(ws + ofs);  ofs = align256(ofs + (size_t)3 * N * sizeof(int));
    int* csr0 = (int*)(ws + ofs);    // E ints
    int* csr1 = csr0 + E;            // 2E ints
    int* csr2 = csr1 + 2 * E;        // 3E ints
    ofs = align256(ofs + (size_t)6 * E * sizeof(int));
    u16* Wp = (u16*)(ws + ofs);      ofs = align256(ofs + (size_t)896 * D * sizeof(u16));
    u16* AG = (u16*)(ws + ofs);

    size_t avail = (ws_size > ofs) ? (ws_size - ofs) : 0;
    long long ncMax = (long long)(avail / (768 * sizeof(u16)));
    int Nc = (int)((ncMax / 128) * 128);
    if (Nc > N) Nc = ((N + 127) / 128) * 128;
    if (Nc < 128) Nc = 128;

    // prep
    zero_int_kernel<<<512, 256, 0, stream>>>(counts, 3 * N + 4);
    convert_x_kernel<<<1024, 256, 0, stream>>>(x, xb, N * D / 4);

    int cb3 = (3 * E + 255) / 256;
    count3_kernel<<<cb3, 256, 0, stream>>>(dst0, dst1, dst2, counts, E, N);

    int bpt = (N + 255) / 256;
    offs_kernel<<<3 * bpt, 256, 0, stream>>>(counts, offs, cursor, counters, N, bpt);

    scatter3_kernel<<<cb3, 256, 0, stream>>>(dst0, src0, dst1, src1, dst2, src2,
                                             cursor, csr0, csr1, csr2, E, N);

    // B matrix: ks 0-1 = WC^T, 2-3 = WA0, 4-7 = WA1, 8-13 = WA2
    pack_all_kernel<<<(14336 + 255) / 256, 256, 0, stream>>>(WC, WA0, WA1, WA2, Wp);

    for (int n0 = 0; n0 < N; n0 += Nc) {
        int M = (N - n0 < Nc) ? (N - n0) : Nc;
        int ab = (3 * M + 3) / 4;
        aggregate_kernel<<<ab, 256, 0, stream>>>(xb, counts, offs, csr0, csr1, csr2,
                                                 AG, n0, M, N);
        final_gemm_kernel<<<(M + 127) / 128, 256, 0, stream>>>(xb, AG, Wp, bC,
                                                               (float*)d_out, n0, M);
    }
}

// Round 3
// 523.638 us; speedup vs baseline: 1.0629x; 1.0629x over previous
//
#include <hip/hip_runtime.h>
#include <hip/hip_bf16.h>

typedef unsigned short u16;
typedef __bf16 bf16x8 __attribute__((ext_vector_type(8)));
typedef float floatx4 __attribute__((ext_vector_type(4)));
typedef unsigned uintx4 __attribute__((ext_vector_type(4)));
typedef unsigned short ushortx4 __attribute__((ext_vector_type(4)));

static constexpr int D = 128;

__device__ inline float bflo(unsigned u) { return __uint_as_float(u << 16); }
__device__ inline float bfhi(unsigned u) { return __uint_as_float(u & 0xffff0000u); }
__device__ inline unsigned packbf(float a, float b) {
    unsigned lo = __hip_bfloat16_raw(__float2bfloat16(a)).x;
    unsigned hi = __hip_bfloat16_raw(__float2bfloat16(b)).x;
    return lo | (hi << 16);
}

// ---------------- zero ints ----------------
__global__ void zero_int_kernel(int* __restrict__ p, int n) {
    int i = blockIdx.x * blockDim.x + threadIdx.x;
    int stride = gridDim.x * blockDim.x;
    for (; i < n; i += stride) p[i] = 0;
}

// ---------------- convert x fp32 -> bf16 ----------------
// x fp32 is read exactly once in the whole pipeline -> nontemporal load.
// xb store stays normal (it is THE reused buffer).
__global__ void convert_x_kernel(const float* __restrict__ x, u16* __restrict__ xb, int n4) {
    int i = blockIdx.x * blockDim.x + threadIdx.x;
    int stride = gridDim.x * blockDim.x;
    for (; i < n4; i += stride) {
        floatx4 v = __builtin_nontemporal_load((const floatx4*)x + i);
        ushortx4 o;
        o.x = __hip_bfloat16_raw(__float2bfloat16(v.x)).x;
        o.y = __hip_bfloat16_raw(__float2bfloat16(v.y)).x;
        o.z = __hip_bfloat16_raw(__float2bfloat16(v.z)).x;
        o.w = __hip_bfloat16_raw(__float2bfloat16(v.w)).x;
        *((ushortx4*)xb + i) = o;
    }
}

// ---------------- per-dst counts: all three edge types in one launch ----------------
// dst is re-read by scatter3 -> keep cached (no NT here).
__global__ void count3_kernel(const int* __restrict__ dst0, const int* __restrict__ dst1,
                              const int* __restrict__ dst2, int* __restrict__ counts,
                              int E, int N) {
    int i = blockIdx.x * blockDim.x + threadIdx.x;
    if (i < E) {
        atomicAdd(&counts[dst0[i]], 1);
    } else if (i < 2 * E) {
        atomicAdd(&counts[N + dst1[i - E]], 1);
    } else if (i < 3 * E) {
        atomicAdd(&counts[2 * N + dst2[i - 2 * E]], 1);
    }
}

// ---------------- offsets: wave scan + one atomic per wave ----------------
// CSR segments need only be disjoint+contiguous per node, not sorted.
__global__ __launch_bounds__(256) void offs_kernel(const int* __restrict__ counts,
                                                   int* __restrict__ offs,
                                                   int* __restrict__ cursor,
                                                   int* __restrict__ counters,
                                                   int N, int bpt) {
    int type = blockIdx.x / bpt;
    int n = (blockIdx.x - type * bpt) * 256 + threadIdx.x;
    int lane = threadIdx.x & 63;
    int i = type * N + n;
    int v = (n < N) ? counts[i] : 0;
    int incl = v;
#pragma unroll
    for (int d = 1; d < 64; d <<= 1) {
        int t = __shfl_up(incl, d, 64);
        if (lane >= d) incl += t;
    }
    int total = __shfl(incl, 63, 64);
    int base = 0;
    if (lane == 63) base = atomicAdd(&counters[type], total);
    base = __shfl(base, 63, 64);
    int off = base + incl - v;
    if (n < N) {
        offs[i] = off;
        cursor[i] = off;
    }
}

// ---------------- CSR scatter (all three edge types, one launch) ----------------
// src/dst are last-use here -> NT loads. csr is re-read by aggregate -> NORMAL stores.
__global__ void scatter3_kernel(const int* __restrict__ dst0, const int* __restrict__ src0,
                                const int* __restrict__ dst1, const int* __restrict__ src1,
                                const int* __restrict__ dst2, const int* __restrict__ src2,
                                int* __restrict__ cursor,
                                int* __restrict__ csr0, int* __restrict__ csr1,
                                int* __restrict__ csr2, int E, int N) {
    int i = blockIdx.x * blockDim.x + threadIdx.x;
    if (i < E) {
        int d = __builtin_nontemporal_load(dst0 + i);
        int pos = atomicAdd(&cursor[d], 1);
        csr0[pos] = __builtin_nontemporal_load(src0 + i);
    } else if (i < 2 * E) {
        int e = i - E;
        int d = __builtin_nontemporal_load(dst1 + e);
        int pos = atomicAdd(&cursor[N + d], 1);
        csr1[pos * 2] = __builtin_nontemporal_load(src1 + e * 2);
        csr1[pos * 2 + 1] = __builtin_nontemporal_load(src1 + e * 2 + 1);
    } else if (i < 3 * E) {
        int e = i - 2 * E;
        int d = __builtin_nontemporal_load(dst2 + e);
        int pos = atomicAdd(&cursor[2 * N + d], 1);
        csr2[pos * 3] = __builtin_nontemporal_load(src2 + e * 3);
        csr2[pos * 3 + 1] = __builtin_nontemporal_load(src2 + e * 3 + 1);
        csr2[pos * 3 + 2] = __builtin_nontemporal_load(src2 + e * 3 + 2);
    }
}

// ---------------- per-node aggregation: one row per wave, lane owns 2 columns ----------------
// Round-3 restructure: the old loop kept exactly ONE gather in flight (observed
// ~650 cy/load fully serialized). Now each chunk issues ALL its gathers
// back-to-back into distinct VGPRs (u[CH_E][A]) before any accumulate, so the
// per-wave chain is offs/counts -> csr -> one gather-latency, not deg*A latencies.
// Guards are wave-uniform s_cbranch in program order (loads first, adds after),
// so batching survives: waits land at the adds, not between loads.
template <int A>
__device__ inline void agg_wave(const u16* __restrict__ xb, const int* __restrict__ csr,
                                int o0, int deg, int lane, u16* __restrict__ outp) {
    constexpr int CH_E = (A == 1) ? 16 : (A == 2) ? 12 : 10;  // edges per chunk
    constexpr int CH = CH_E * A;                              // csr items per chunk (<=64)
    float acc[A][2];
#pragma unroll
    for (int s = 0; s < A; ++s) {
        acc[s][0] = 0.f;
        acc[s][1] = 0.f;
    }
    const int items = deg * A;
    const int base = o0 * A;
    const unsigned* __restrict__ xw = (const unsigned*)xb;

    for (int e0 = 0; e0 < deg; e0 += CH_E) {
        int ib = e0 * A;
        int rv = 0;
        if (lane < CH && ib + lane < items) rv = csr[base + ib + lane];
        int erem = deg - e0;  // wave-uniform
        if (erem > CH_E) erem = CH_E;
        unsigned u[CH_E][A];
        // ---- issue all gathers for this chunk (no accumulates in between) ----
#pragma unroll
        for (int ke = 0; ke < CH_E; ++ke) {
            if (ke < erem) {
#pragma unroll
                for (int s = 0; s < A; ++s) {
                    int r = __builtin_amdgcn_readlane(rv, ke * A + s);  // SGPR row id
                    u[ke][s] = xw[((size_t)(unsigned)r << 6) + lane];
                }
            }
        }
        // ---- accumulate ----
#pragma unroll
        for (int ke = 0; ke < CH_E; ++ke) {
            if (ke < erem) {
#pragma unroll
                for (int s = 0; s < A; ++s) {
                    acc[s][0] += bflo(u[ke][s]);
                    acc[s][1] += bfhi(u[ke][s]);
                }
            }
        }
    }

    float norm = (deg > 0) ? 1.0f / (float)deg : 0.0f;
#pragma unroll
    for (int s = 0; s < A; ++s) {
        unsigned o = packbf(acc[s][0] * norm, acc[s][1] * norm);
        ((unsigned*)(outp + s * D))[lane] = o;  // normal store: gemm re-reads AG
    }
}

__global__ __launch_bounds__(256) void aggregate_kernel(
    const u16* __restrict__ xb, const int* __restrict__ counts, const int* __restrict__ offs,
    const int* __restrict__ csr0, const int* __restrict__ csr1, const int* __restrict__ csr2,
    u16* __restrict__ AG, int n0, int M, int N) {
    int w = __builtin_amdgcn_readfirstlane(threadIdx.x >> 6);
    int gw = blockIdx.x * 4 + w;
    int lane = threadIdx.x & 63;
    if (gw >= 3 * M) return;
    int type = (gw >= 2 * M) ? 2 : (gw >= M) ? 1 : 0;
    int l = gw - type * M;
    int n = n0 + l;
    u16* outp = AG + (size_t)l * 768;
    if (type == 0) {
        int o0 = __builtin_amdgcn_readfirstlane(offs[n]);
        int dg = __builtin_amdgcn_readfirstlane(counts[n]);
        agg_wave<1>(xb, csr0, o0, dg, lane, outp);
    } else if (type == 1) {
        int o0 = __builtin_amdgcn_readfirstlane(offs[N + n]);
        int dg = __builtin_amdgcn_readfirstlane(counts[N + n]);
        agg_wave<2>(xb, csr1, o0, dg, lane, outp + 128);
    } else {
        int o0 = __builtin_amdgcn_readfirstlane(offs[2 * N + n]);
        int dg = __builtin_amdgcn_readfirstlane(counts[2 * N + n]);
        agg_wave<3>(xb, csr2, o0, dg, lane, outp + 384);
    }
}

// ---------------- pack fp32 weights into bf16 MFMA B-fragment order (one launch) ----------------
// Wp layout (u16): [0,16384)=WC^T, [16384,32768)=WA0, [32768,65536)=WA1, [65536,163840)=WA2
__global__ void pack_all_kernel(const float* __restrict__ WC, const float* __restrict__ WA0,
                                const float* __restrict__ WA1, const float* __restrict__ WA2,
                                u16* __restrict__ Wp) {
    int c = blockIdx.x * blockDim.x + threadIdx.x;  // 0 .. 14335 chunks
    if (c >= 14336) return;
    const float* W;
    int K, transposed, cl;
    u16* out;
    if (c < 2048) {
        W = WC; K = 128; transposed = 1; cl = c; out = Wp;
    } else if (c < 4096) {
        W = WA0; K = 128; transposed = 0; cl = c - 2048; out = Wp + 16384;
    } else if (c < 8192) {
        W = WA1; K = 256; transposed = 0; cl = c - 4096; out = Wp + 32768;
    } else {
        W = WA2; K = 384; transposed = 0; cl = c - 8192; out = Wp + 65536;
    }
    int s = cl >> 9, rem = cl & 511, t = rem >> 6, l = rem & 63;
    int kbase = 32 * s + ((l >> 4) * 8);
    int n = 16 * t + (l & 15);
#pragma unroll
    for (int j = 0; j < 8; ++j) {
        int k = kbase + j;
        float w = transposed ? W[n * K + k] : W[k * D + n];
        out[(size_t)cl * 8 + j] = __hip_bfloat16_raw(__float2bfloat16(w)).x;
    }
}

// ---------------- fused final GEMM: out = [x | AG] @ [WC^T; WA*] + bC ----------------
__global__ __launch_bounds__(256) void final_gemm_kernel(
    const u16* __restrict__ xb, const u16* __restrict__ AG, const u16* __restrict__ Wp,
    const float* __restrict__ bC, float* __restrict__ out, int n0, int M) {
    constexpr int KSTEPS = 14;  // 896 / 64
    alignas(16) __shared__ u16 As[128][72];
    alignas(16) __shared__ u16 Bs[8192];

    const int tid = threadIdx.x;
    const int wave = tid >> 6;
    const int lane = tid & 63;
    const int m0 = blockIdx.x * 128;

    floatx4 acc[2][8];
#pragma unroll
    for (int s = 0; s < 2; ++s)
#pragma unroll
        for (int t = 0; t < 8; ++t) acc[s][t] = floatx4{0.f, 0.f, 0.f, 0.f};

    for (int ks = 0; ks < KSTEPS; ++ks) {
#pragma unroll
        for (int it = 0; it < 4; ++it) {
            int chunk = tid + it * 256;
            int row = chunk >> 3, part = chunk & 7;
            int e = m0 + row;
            const u16* srcp;
            if (ks < 2) {
                int g = (e < M) ? (n0 + e) : n0;
                srcp = xb + (size_t)g * D + ks * 64;
            } else {
                int l = (e < M) ? e : 0;
                srcp = AG + (size_t)l * 768 + (ks - 2) * 64;
            }
            *(uintx4*)(&As[row][part * 8]) = *(const uintx4*)(srcp + part * 8);
        }
        {
            const uintx4* sB = (const uintx4*)(Wp + (size_t)ks * 8192);
            uintx4* dB = (uintx4*)Bs;
#pragma unroll
            for (int it = 0; it < 4; ++it) dB[tid + it * 256] = sB[tid + it * 256];
        }
        __syncthreads();
#pragma unroll
        for (int sub = 0; sub < 2; ++sub) {
            bf16x8 bfrag[8];
#pragma unroll
            for (int t = 0; t < 8; ++t)
                bfrag[t] = *(const bf16x8*)(&Bs[((sub * 8 + t) * 64 + lane) * 8]);
#pragma unroll
            for (int strip = 0; strip < 2; ++strip) {
                int row = wave * 32 + strip * 16 + (lane & 15);
                bf16x8 afrag = *(const bf16x8*)(&As[row][sub * 32 + ((lane >> 4) * 8)]);
#pragma unroll
                for (int t = 0; t < 8; ++t)
                    acc[strip][t] = __builtin_amdgcn_mfma_f32_16x16x32_bf16(
                        afrag, bfrag[t], acc[strip][t], 0, 0, 0);
            }
        }
        __syncthreads();
    }

#pragma unroll
    for (int strip = 0; strip < 2; ++strip) {
#pragma unroll
        for (int r = 0; r < 4; ++r) {
            int row = wave * 32 + strip * 16 + (lane >> 4) * 4 + r;
            int e = m0 + row;
            if (e >= M) continue;
            size_t base = (size_t)(n0 + e) * D;
#pragma unroll
            for (int t = 0; t < 8; ++t) {
                int col = 16 * t + (lane & 15);
                out[base + col] = acc[strip][t][r] + bC[col];
            }
        }
    }
}

extern "C" void kernel_launch(void* const* d_in, const int* in_sizes, int n_in,
                              void* d_out, int out_size, void* d_ws, size_t ws_size,
                              hipStream_t stream) {
    const float* x = (const float*)d_in[0];
    const int* src0 = (const int*)d_in[1];
    const int* dst0 = (const int*)d_in[2];
    const int* src1 = (const int*)d_in[3];
    const int* dst1 = (const int*)d_in[4];
    const int* src2 = (const int*)d_in[5];
    const int* dst2 = (const int*)d_in[6];
    const float* WA0 = (const float*)d_in[7];
    const float* WA1 = (const float*)d_in[8];
    const float* WA2 = (const float*)d_in[9];
    const float* WC = (const float*)d_in[10];
    const float* bC = (const float*)d_in[11];

    const int N = in_sizes[0] / D;  // 100000
    const int E = in_sizes[2];      // 500000

    auto align256 = [](size_t v) { return (v + 255) & ~(size_t)255; };
    char* ws = (char*)d_ws;
    size_t ofs = 0;
    u16* xb = (u16*)(ws + ofs);      ofs = align256(ofs + (size_t)N * D * sizeof(u16));
    int* counts = (int*)(ws + ofs);  ofs = align256(ofs + ((size_t)3 * N + 4) * sizeof(int));
    int* counters = counts + 3 * N;  // 3 ints, zeroed with counts
    int* offs = (int*)(ws + ofs);    ofs = align256(ofs + (size_t)3 * N * sizeof(int));
    int* cursor = (int*)(ws + ofs);  ofs = align256(ofs + (size_t)3 * N * sizeof(int));
    int* csr0 = (int*)(ws + ofs);    // E ints
    int* csr1 = csr0 + E;            // 2E ints
    int* csr2 = csr1 + 2 * E;        // 3E ints
    ofs = align256(ofs + (size_t)6 * E * sizeof(int));
    u16* Wp = (u16*)(ws + ofs);      ofs = align256(ofs + (size_t)896 * D * sizeof(u16));
    u16* AG = (u16*)(ws + ofs);

    size_t avail = (ws_size > ofs) ? (ws_size - ofs) : 0;
    long long ncMax = (long long)(avail / (768 * sizeof(u16)));
    int Nc = (int)((ncMax / 128) * 128);
    if (Nc > N) Nc = ((N + 127) / 128) * 128;
    if (Nc < 128) Nc = 128;

    // prep
    zero_int_kernel<<<512, 256, 0, stream>>>(counts, 3 * N + 4);
    convert_x_kernel<<<1024, 256, 0, stream>>>(x, xb, N * D / 4);

    int cb3 = (3 * E + 255) / 256;
    count3_kernel<<<cb3, 256, 0, stream>>>(dst0, dst1, dst2, counts, E, N);

    int bpt = (N + 255) / 256;
    offs_kernel<<<3 * bpt, 256, 0, stream>>>(counts, offs, cursor, counters, N, bpt);

    scatter3_kernel<<<cb3, 256, 0, stream>>>(dst0, src0, dst1, src1, dst2, src2,
                                             cursor, csr0, csr1, csr2, E, N);

    // B matrix: ks 0-1 = WC^T, 2-3 = WA0, 4-7 = WA1, 8-13 = WA2
    pack_all_kernel<<<(14336 + 255) / 256, 256, 0, stream>>>(WC, WA0, WA1, WA2, Wp);

    for (int n0 = 0; n0 < N; n0 += Nc) {
        int M = (N - n0 < Nc) ? (N - n0) : Nc;
        int ab = (3 * M + 3) / 4;
        aggregate_kernel<<<ab, 256, 0, stream>>>(xb, counts, offs, csr0, csr1, csr2,
                                                 AG, n0, M, N);
        final_gemm_kernel<<<(M + 127) / 128, 256, 0, stream>>>(xb, AG, Wp, bC,
                                                               (float*)d_out, n0, M);
    }
}